// Round 5
// baseline (19928.873 us; speedup 1.0000x reference)
//
#include <hip/hip_runtime.h>
#include <hip/hip_cooperative_groups.h>

namespace cg = cooperative_groups;

#define T_STEPS 512
#define BATCH   64
#define EDIM    256
#define HDIM    512
#define HB      (BATCH * HDIM)          // elements of one h-state slot (32768)
#define NL      18                      // k-slices cached in LDS (per WG): 18*8KB = 144KB

typedef __attribute__((ext_vector_type(8))) short  bf16x8;
typedef __attribute__((ext_vector_type(4))) float  f32x4;
typedef unsigned short ushort_t;

// ---------- bf16 helpers ----------
__device__ __forceinline__ unsigned short f2bf(float x) {
    unsigned u = __float_as_uint(x);
    u += 0x7fffu + ((u >> 16) & 1u);
    return (unsigned short)(u >> 16);
}
__device__ __forceinline__ float bf2f(unsigned short h) {
    return __uint_as_float(((unsigned)h) << 16);
}

// ---------- activations ----------
__device__ __forceinline__ float sigm(float x) {
    x = fminf(fmaxf(x, -30.f), 30.f);
    return 1.f / (1.f + __expf(-x));
}
__device__ __forceinline__ float tanh_f(float x) {
    x = fminf(fmaxf(x, -15.f), 15.f);
    float e = __expf(2.f * x);
    return (e - 1.f) / (e + 1.f);
}

// workspace layout (ushort elements)  -- total ~32.0 MB
#define OFF_XEHI  ((size_t)0)
#define SZ_XEHI   ((size_t)T_STEPS * BATCH * EDIM)          // 8388608
#define OFF_H0HI  (OFF_XEHI + SZ_XEHI)
#define OFF_H0LO  (OFF_H0HI + 2 * HB)
#define OFF_H1HI  (OFF_H0LO + 2 * HB)
#define OFF_H1LO  (OFF_H1HI + 2 * HB)
#define OFF_B0HI  (OFF_H1LO + 2 * HB)
#define SZ_BPK0   ((size_t)32 * 4 * 24 * 64 * 8)            // 1572864
#define OFF_B0LO  (OFF_B0HI + SZ_BPK0)
#define OFF_B1HI  (OFF_B0LO + SZ_BPK0)
#define SZ_BPK1   ((size_t)32 * 4 * 32 * 64 * 8)            // 2097152
#define OFF_B1LO  (OFF_B1HI + SZ_BPK1)

// ---------- prep: gather embeddings -> bf16 row-major [t][b][256] ----------
__global__ __launch_bounds__(256) void xepack_kernel(const int* __restrict__ x,
                                                     const float* __restrict__ emb,
                                                     ushort_t* __restrict__ XeHi) {
    int tid = blockIdx.x * 256 + threadIdx.x;          // 1,048,576 threads
    int c8 = tid & 31;
    int b  = (tid >> 5) & 63;
    int t  = tid >> 11;
    int idx = x[b * T_STEPS + t];
    const float4* e = (const float4*)(emb + (size_t)idx * EDIM + c8 * 8);
    float4 f0 = e[0], f1 = e[1];
    ushort_t v[8];
    v[0] = f2bf(f0.x); v[1] = f2bf(f0.y); v[2] = f2bf(f0.z); v[3] = f2bf(f0.w);
    v[4] = f2bf(f1.x); v[5] = f2bf(f1.y); v[6] = f2bf(f1.z); v[7] = f2bf(f1.w);
    ushort_t* dst = XeHi + ((size_t)t * BATCH + b) * EDIM + c8 * 8;
    *(uint4*)dst = *(uint4*)v;
}

// ---------- prep: pack weights into B-fragment order, bf16 hi/lo pair ----------
// Bpk flat index: (((u*4 + g)*KS + ks)*64 + lane)*8, element j:
//   k = ks*32 + (lane>>4)*8 + j, col n = g*512 + u*16 + (lane&15), value W[n][k]
__global__ __launch_bounds__(256) void wpack_kernel(const float* __restrict__ Wih0, const float* __restrict__ Whh0,
                                                    const float* __restrict__ Wih1, const float* __restrict__ Whh1,
                                                    ushort_t* __restrict__ B0hi, ushort_t* __restrict__ B0lo,
                                                    ushort_t* __restrict__ B1hi, ushort_t* __restrict__ B1lo) {
    const int NT0 = 32 * 4 * 24 * 64;   // 196608
    const int NT1 = 32 * 4 * 32 * 64;   // 262144
    int tid = blockIdx.x * 256 + threadIdx.x;
    if (tid >= NT0 + NT1) return;
    int layer, idx, KS;
    ushort_t *dhi, *dlo;
    if (tid < NT0) { layer = 0; idx = tid;        KS = 24; dhi = B0hi; dlo = B0lo; }
    else           { layer = 1; idx = tid - NT0;  KS = 32; dhi = B1hi; dlo = B1lo; }
    int lane = idx & 63;
    int t1 = idx >> 6;
    int ks = t1 % KS;
    int t2 = t1 / KS;
    int g = t2 & 3;
    int u = t2 >> 2;
    int n = g * HDIM + u * 16 + (lane & 15);
    int k = ks * 32 + (lane >> 4) * 8;
    const float* src;
    if (layer == 0) src = (k < EDIM) ? (Wih0 + (size_t)n * EDIM + k) : (Whh0 + (size_t)n * HDIM + (k - EDIM));
    else            src = (k < HDIM) ? (Wih1 + (size_t)n * HDIM + k) : (Whh1 + (size_t)n * HDIM + (k - HDIM));
    const float4* s4 = (const float4*)src;
    float4 f0 = s4[0], f1 = s4[1];
    float f[8] = {f0.x, f0.y, f0.z, f0.w, f1.x, f1.y, f1.z, f1.w};
    ushort_t vh[8], vl[8];
    #pragma unroll
    for (int j = 0; j < 8; ++j) {
        vh[j] = f2bf(f[j]);
        vl[j] = f2bf(f[j] - bf2f(vh[j]));
    }
    *(uint4*)(dhi + (size_t)idx * 8) = *(uint4*)vh;
    *(uint4*)(dlo + (size_t)idx * 8) = *(uint4*)vl;
}

// ---------- prep: zero the h-state buffers ----------
__global__ void zero_kernel(unsigned int* __restrict__ p, int n) {
    int i = blockIdx.x * blockDim.x + threadIdx.x;
    if (i < n) p[i] = 0u;
}

// ---------- main persistent cooperative kernel ----------
// 256 WGs x 128 threads (2 waves). WG w: layer = w>>7; u=(w>>2)&31; bt=w&3.
// Weight B-fragments for ks < NL live in LDS (staged once); rest from global (L2).
// wave0: cached ks [0,NL/2) + residual [NL, NL+(KS-NL)/2); wave1: the other halves.
__global__ __launch_bounds__(128, 1) void lstm_main(
    const ushort_t* __restrict__ XeHi,
    ushort_t* __restrict__ H0hi, ushort_t* __restrict__ H0lo,
    ushort_t* __restrict__ H1hi, ushort_t* __restrict__ H1lo,
    const ushort_t* __restrict__ B0hi, const ushort_t* __restrict__ B0lo,
    const ushort_t* __restrict__ B1hi, const ushort_t* __restrict__ B1lo,
    const float* __restrict__ bias0, const float* __restrict__ bias1,
    const float* __restrict__ Wclf, const float* __restrict__ bclf,
    float* __restrict__ out)
{
    cg::grid_group grid = cg::this_grid();
    __shared__ float red[4][4][64];
    // LDS weight cache: frag fid = (ks*2+buf)*4+g, 512 ushorts each; 144KB total
    __shared__ ushort_t wlds[NL * 8 * 512];

    const int lane = threadIdx.x & 63;
    const int wv   = threadIdx.x >> 6;          // 0 or 1
    const int wg   = blockIdx.x;
    const int layer = wg >> 7;
    const int rr   = wg & 127;
    const int u    = rr >> 2;
    const int bt   = rr & 3;
    const int KS   = layer ? 32 : 24;
    const ushort_t* Bhi = layer ? B1hi : B0hi;
    const ushort_t* Blo = layer ? B1lo : B0lo;
    const float* bias   = layer ? bias1 : bias0;

    // per-wave k-slice schedule: nc cached + nr residual
    const int nc   = NL / 2;                            // 9
    const int cBeg = wv ? NL / 2 : 0;
    const int rBeg = NL + (wv ? (KS - NL) / 2 : 0);
    const int nr   = (KS - NL) / 2;                     // 3 (L0) or 7 (L1)
    const int n    = nc + nr;

    // hoisted per-lane constants
    const int rowA = bt * 16 + (lane & 15);     // batch row for A-frags
    const int koffA = (lane >> 4) * 8;
    const size_t gs    = (size_t)KS * 512;      // gate stride in packed B
    const size_t bBase = (size_t)(u * 4) * gs + (size_t)lane * 8;
    float bg0 = bias[0 * HDIM + u * 16 + (lane & 15)];
    float bg1 = bias[1 * HDIM + u * 16 + (lane & 15)];
    float bg2 = bias[2 * HDIM + u * 16 + (lane & 15)];
    float bg3 = bias[3 * HDIM + u * 16 + (lane & 15)];

    // ---- stage weight k-slices [0, NL) into LDS (once) ----
    for (int fid = wv * 64 + lane; fid < NL * 8; fid += 128) {
        // fid = (ks*2+buf)*4+g ; copy whole 1KB frag cooperatively? No: one lane
        // copies 16B of 64 different lanes' slots would break layout. Instead:
        // each (fid) entry here moves ONE lane-slot of frag (fid>>0)... simpler:
        // loop frags with full wave below.
        break;
    }
    // full-wave staging: wave wv handles frags fid = wv, wv+2, ...
    for (int fid = wv; fid < NL * 8; fid += 2) {
        int ks  = fid >> 3;
        int buf = (fid >> 2) & 1;
        int g   = fid & 3;
        const ushort_t* src = (buf ? Blo : Bhi) + bBase + (size_t)g * gs + (size_t)ks * 512;
        *(bf16x8*)(wlds + (size_t)fid * 512 + lane * 8) = *(const bf16x8*)src;
    }
    __syncthreads();

    f32x4 cst = {0.f, 0.f, 0.f, 0.f};           // persistent c-state (owner wave)

    for (int p = 0; p <= T_STEPS; ++p) {
        const bool active = layer ? (p >= 1) : (p < T_STEPS);
        f32x4 acc0 = {0,0,0,0}, acc1 = {0,0,0,0}, acc2 = {0,0,0,0}, acc3 = {0,0,0,0};

        if (active) {
            auto ksOf = [&](int i) { return (i < nc) ? (cBeg + i) : (rBeg + (i - nc)); };
            // ---- A fragments (h-state / embeddings) from global ----
            auto loadA = [&](int ks, bf16x8& ah, bf16x8& al, int& haslo) {
                const ushort_t* hi; const ushort_t* lo = nullptr; int ld, kl;
                if (layer == 0) {
                    if (ks < 8) { hi = XeHi + (size_t)p * (BATCH * EDIM); ld = EDIM; kl = ks; }
                    else { int s = (p - 1) & 1; hi = H0hi + (size_t)s * HB; lo = H0lo + (size_t)s * HB; ld = HDIM; kl = ks - 8; }
                } else {
                    if (ks < 16) { int s = (p - 1) & 1; hi = H0hi + (size_t)s * HB; lo = H0lo + (size_t)s * HB; ld = HDIM; kl = ks; }
                    else         { int s = p & 1;       hi = H1hi + (size_t)s * HB; lo = H1lo + (size_t)s * HB; ld = HDIM; kl = ks - 16; }
                }
                size_t off = (size_t)rowA * ld + kl * 32 + koffA;
                ah = *(const bf16x8*)(hi + off);
                haslo = (lo != nullptr);
                if (lo) al = *(const bf16x8*)(hi == nullptr ? hi : (lo + off));
            };
            // ---- B fragments: LDS if cached, else global ----
            auto loadB = [&](int i, bf16x8* bh, bf16x8* bl) {
                int ks = ksOf(i);
                if (i < nc) {
                    const ushort_t* p8 = wlds + (size_t)(8 * ks) * 512 + lane * 8;
                    #pragma unroll
                    for (int g = 0; g < 4; ++g) {
                        bh[g] = *(const bf16x8*)(p8 + (size_t)g * 512);
                        bl[g] = *(const bf16x8*)(p8 + (size_t)(4 + g) * 512);
                    }
                } else {
                    const size_t o = bBase + (size_t)ks * 512;
                    #pragma unroll
                    for (int g = 0; g < 4; ++g) {
                        bh[g] = *(const bf16x8*)(Bhi + o + g * gs);
                        bl[g] = *(const bf16x8*)(Blo + o + g * gs);
                    }
                }
            };

            bf16x8 cah, cal, cbh[4], cbl[4]; int chl;
            loadA(ksOf(0), cah, cal, chl);
            loadB(0, cbh, cbl);
            #pragma unroll 2
            for (int i = 0; i < n; ++i) {
                bf16x8 nah = cah, nal = cal, nbh[4], nbl[4]; int nhl = chl;
                #pragma unroll
                for (int g = 0; g < 4; ++g) { nbh[g] = cbh[g]; nbl[g] = cbl[g]; }
                if (i + 1 < n) {
                    loadA(ksOf(i + 1), nah, nal, nhl);
                    loadB(i + 1, nbh, nbl);
                }
                // 3-term products: hi*hi + hi*lo + lo*hi  (lo*lo dropped, ~2^-18)
                acc0 = __builtin_amdgcn_mfma_f32_16x16x32_bf16(cah, cbh[0], acc0, 0, 0, 0);
                acc1 = __builtin_amdgcn_mfma_f32_16x16x32_bf16(cah, cbh[1], acc1, 0, 0, 0);
                acc2 = __builtin_amdgcn_mfma_f32_16x16x32_bf16(cah, cbh[2], acc2, 0, 0, 0);
                acc3 = __builtin_amdgcn_mfma_f32_16x16x32_bf16(cah, cbh[3], acc3, 0, 0, 0);
                acc0 = __builtin_amdgcn_mfma_f32_16x16x32_bf16(cah, cbl[0], acc0, 0, 0, 0);
                acc1 = __builtin_amdgcn_mfma_f32_16x16x32_bf16(cah, cbl[1], acc1, 0, 0, 0);
                acc2 = __builtin_amdgcn_mfma_f32_16x16x32_bf16(cah, cbl[2], acc2, 0, 0, 0);
                acc3 = __builtin_amdgcn_mfma_f32_16x16x32_bf16(cah, cbl[3], acc3, 0, 0, 0);
                if (chl) {
                    acc0 = __builtin_amdgcn_mfma_f32_16x16x32_bf16(cal, cbh[0], acc0, 0, 0, 0);
                    acc1 = __builtin_amdgcn_mfma_f32_16x16x32_bf16(cal, cbh[1], acc1, 0, 0, 0);
                    acc2 = __builtin_amdgcn_mfma_f32_16x16x32_bf16(cal, cbh[2], acc2, 0, 0, 0);
                    acc3 = __builtin_amdgcn_mfma_f32_16x16x32_bf16(cal, cbh[3], acc3, 0, 0, 0);
                }
                cah = nah; cal = nal; chl = nhl;
                #pragma unroll
                for (int g = 0; g < 4; ++g) { cbh[g] = nbh[g]; cbl[g] = nbl[g]; }
            }

            if (wv == 1) {
                #pragma unroll
                for (int r = 0; r < 4; ++r) {
                    red[0][r][lane] = acc0[r];
                    red[1][r][lane] = acc1[r];
                    red[2][r][lane] = acc2[r];
                    red[3][r][lane] = acc3[r];
                }
            }
        }
        __syncthreads();
        if (active && wv == 0) {
            // reduce + bias + LSTM cell (all in-register; c never leaves VGPRs)
            ushort_t* Whi = layer ? (H1hi + (size_t)((p - 1) & 1) * HB) : (H0hi + (size_t)(p & 1) * HB);
            ushort_t* Wlo = layer ? (H1lo + (size_t)((p - 1) & 1) * HB) : (H0lo + (size_t)(p & 1) * HB);
            #pragma unroll
            for (int r = 0; r < 4; ++r) {
                float gi = acc0[r] + red[0][r][lane] + bg0;
                float gf = acc1[r] + red[1][r][lane] + bg1;
                float gg = acc2[r] + red[2][r][lane] + bg2;
                float go = acc3[r] + red[3][r][lane] + bg3;
                float ig = sigm(gi), fg = sigm(gf), gc = tanh_f(gg), og = sigm(go);
                float cn = fg * cst[r] + ig * gc;
                cst[r] = cn;
                float h = og * tanh_f(cn);
                int b = bt * 16 + (lane >> 4) * 4 + r;
                int cidx = u * 16 + (lane & 15);
                unsigned short hh = f2bf(h);
                float hf = bf2f(hh);
                unsigned short hl = f2bf(h - hf);
                Whi[(size_t)b * HDIM + cidx] = hh;
                Wlo[(size_t)b * HDIM + cidx] = hl;
            }
        }
        grid.sync();
    }

    // ---------- classifier: out = h1_final @ Wclf^T + bclf ----------
    if (wg == 0 && wv == 0) {
        int b = lane;
        float a0 = bclf[0], a1 = bclf[1];
        const ushort_t* hh = H1hi + HB;   // final h1 in slot 1
        const ushort_t* hl = H1lo + HB;
        #pragma unroll 8
        for (int k = 0; k < HDIM; ++k) {
            float h = bf2f(hh[(size_t)b * HDIM + k]) + bf2f(hl[(size_t)b * HDIM + k]);
            a0 = fmaf(h, Wclf[k], a0);
            a1 = fmaf(h, Wclf[HDIM + k], a1);
        }
        out[b * 2 + 0] = a0;
        out[b * 2 + 1] = a1;
    }
}

extern "C" void kernel_launch(void* const* d_in, const int* in_sizes, int n_in,
                              void* d_out, int out_size, void* d_ws, size_t ws_size,
                              hipStream_t stream) {
    const int*   x     = (const int*)d_in[0];
    const float* emb   = (const float*)d_in[1];
    const float* Wih0  = (const float*)d_in[2];
    const float* Whh0  = (const float*)d_in[3];
    const float* bias0 = (const float*)d_in[4];
    const float* Wih1  = (const float*)d_in[5];
    const float* Whh1  = (const float*)d_in[6];
    const float* bias1 = (const float*)d_in[7];
    const float* Wclf  = (const float*)d_in[8];
    const float* bclf  = (const float*)d_in[9];
    float* out = (float*)d_out;

    ushort_t* ws   = (ushort_t*)d_ws;
    ushort_t* XeHi = ws + OFF_XEHI;
    ushort_t* H0hi = ws + OFF_H0HI;
    ushort_t* H0lo = ws + OFF_H0LO;
    ushort_t* H1hi = ws + OFF_H1HI;
    ushort_t* H1lo = ws + OFF_H1LO;
    ushort_t* B0hi = ws + OFF_B0HI;
    ushort_t* B0lo = ws + OFF_B0LO;
    ushort_t* B1hi = ws + OFF_B1HI;
    ushort_t* B1lo = ws + OFF_B1LO;

    // 1) gather+convert embeddings: 1,048,576 threads
    xepack_kernel<<<4096, 256, 0, stream>>>(x, emb, XeHi);
    // 2) pack weights (hi/lo) to fragment order: 458,752 threads
    wpack_kernel<<<1793, 256, 0, stream>>>(Wih0, Whh0, Wih1, Whh1, B0hi, B0lo, B1hi, B1lo);
    // 3) zero h-state buffers (8 * HB ushorts = 131072 uints)
    zero_kernel<<<512, 256, 0, stream>>>((unsigned int*)H0hi, 8 * HB / 2);
    // 4) persistent cooperative LSTM
    void* args[] = {
        (void*)&XeHi,
        (void*)&H0hi, (void*)&H0lo, (void*)&H1hi, (void*)&H1lo,
        (void*)&B0hi, (void*)&B0lo, (void*)&B1hi, (void*)&B1lo,
        (void*)&bias0, (void*)&bias1,
        (void*)&Wclf, (void*)&bclf,
        (void*)&out
    };
    hipLaunchCooperativeKernel((void*)lstm_main, dim3(256), dim3(128), args, 0, stream);
}

// Round 6
// 10173.884 us; speedup vs baseline: 1.9588x; 1.9588x over previous
//
#include <hip/hip_runtime.h>

#define T_STEPS 512
#define BATCH   64
#define EDIM    256
#define HDIM    512
#define HB      (BATCH * HDIM)          // uints per h-state slot (32768)
#define NL      18                      // k-slices cached in LDS (per WG): 18*8KB = 144KB
#define NWG     256

typedef __attribute__((ext_vector_type(8))) short  bf16x8;
typedef __attribute__((ext_vector_type(4))) float  f32x4;
typedef unsigned short ushort_t;
typedef unsigned int   uint_t;

// ---------- bf16 helpers ----------
__device__ __forceinline__ unsigned short f2bf(float x) {
    unsigned u = __float_as_uint(x);
    u += 0x7fffu + ((u >> 16) & 1u);
    return (unsigned short)(u >> 16);
}
__device__ __forceinline__ float bf2f(unsigned short h) {
    return __uint_as_float(((unsigned)h) << 16);
}

// ---------- activations ----------
__device__ __forceinline__ float sigm(float x) {
    x = fminf(fmaxf(x, -30.f), 30.f);
    return 1.f / (1.f + __expf(-x));
}
__device__ __forceinline__ float tanh_f(float x) {
    x = fminf(fmaxf(x, -15.f), 15.f);
    float e = __expf(2.f * x);
    return (e - 1.f) / (e + 1.f);
}

// ---------- workspace byte offsets ----------
// XeHi   : ushort[512*64*256]  @ 0         (16,777,216 B)
// Hcomb0 : uint[2*HB]          @ 16777216  (262,144 B)   h0 slots, hi|lo<<16
// Hcomb1 : uint[2*HB]          @ 17039360  (262,144 B)   h1 slots
// bar    : uint[64]            @ 17301504  (256 B)       [0]=cnt, [32]=flag
// B0hi   : ushort[1572864]     @ 17301760
// B0lo   : ushort[1572864]     @ 20447488
// B1hi   : ushort[2097152]     @ 23593216
// B1lo   : ushort[2097152]     @ 27787520   (end 31,981,824 B)
#define BYTE_XEHI   ((size_t)0)
#define BYTE_HC0    ((size_t)16777216)
#define BYTE_HC1    ((size_t)17039360)
#define BYTE_BAR    ((size_t)17301504)
#define BYTE_B0HI   ((size_t)17301760)
#define BYTE_B0LO   ((size_t)20447488)
#define BYTE_B1HI   ((size_t)23593216)
#define BYTE_B1LO   ((size_t)27787520)

// ---------- prep: gather embeddings -> bf16 row-major [t][b][256] ----------
__global__ __launch_bounds__(256) void xepack_kernel(const int* __restrict__ x,
                                                     const float* __restrict__ emb,
                                                     ushort_t* __restrict__ XeHi) {
    int tid = blockIdx.x * 256 + threadIdx.x;          // 1,048,576 threads
    int c8 = tid & 31;
    int b  = (tid >> 5) & 63;
    int t  = tid >> 11;
    int idx = x[b * T_STEPS + t];
    const float4* e = (const float4*)(emb + (size_t)idx * EDIM + c8 * 8);
    float4 f0 = e[0], f1 = e[1];
    ushort_t v[8];
    v[0] = f2bf(f0.x); v[1] = f2bf(f0.y); v[2] = f2bf(f0.z); v[3] = f2bf(f0.w);
    v[4] = f2bf(f1.x); v[5] = f2bf(f1.y); v[6] = f2bf(f1.z); v[7] = f2bf(f1.w);
    ushort_t* dst = XeHi + ((size_t)t * BATCH + b) * EDIM + c8 * 8;
    *(uint4*)dst = *(uint4*)v;
}

// ---------- prep: pack weights into B-fragment order, bf16 hi/lo pair ----------
__global__ __launch_bounds__(256) void wpack_kernel(const float* __restrict__ Wih0, const float* __restrict__ Whh0,
                                                    const float* __restrict__ Wih1, const float* __restrict__ Whh1,
                                                    ushort_t* __restrict__ B0hi, ushort_t* __restrict__ B0lo,
                                                    ushort_t* __restrict__ B1hi, ushort_t* __restrict__ B1lo) {
    const int NT0 = 32 * 4 * 24 * 64;   // 196608
    const int NT1 = 32 * 4 * 32 * 64;   // 262144
    int tid = blockIdx.x * 256 + threadIdx.x;
    if (tid >= NT0 + NT1) return;
    int layer, idx, KS;
    ushort_t *dhi, *dlo;
    if (tid < NT0) { layer = 0; idx = tid;        KS = 24; dhi = B0hi; dlo = B0lo; }
    else           { layer = 1; idx = tid - NT0;  KS = 32; dhi = B1hi; dlo = B1lo; }
    int lane = idx & 63;
    int t1 = idx >> 6;
    int ks = t1 % KS;
    int t2 = t1 / KS;
    int g = t2 & 3;
    int u = t2 >> 2;
    int n = g * HDIM + u * 16 + (lane & 15);
    int k = ks * 32 + (lane >> 4) * 8;
    const float* src;
    if (layer == 0) src = (k < EDIM) ? (Wih0 + (size_t)n * EDIM + k) : (Whh0 + (size_t)n * HDIM + (k - EDIM));
    else            src = (k < HDIM) ? (Wih1 + (size_t)n * HDIM + k) : (Whh1 + (size_t)n * HDIM + (k - HDIM));
    const float4* s4 = (const float4*)src;
    float4 f0 = s4[0], f1 = s4[1];
    float f[8] = {f0.x, f0.y, f0.z, f0.w, f1.x, f1.y, f1.z, f1.w};
    ushort_t vh[8], vl[8];
    #pragma unroll
    for (int j = 0; j < 8; ++j) {
        vh[j] = f2bf(f[j]);
        vl[j] = f2bf(f[j] - bf2f(vh[j]));
    }
    *(uint4*)(dhi + (size_t)idx * 8) = *(uint4*)vh;
    *(uint4*)(dlo + (size_t)idx * 8) = *(uint4*)vl;
}

// ---------- prep: zero h-state + barrier vars ----------
__global__ void zero_kernel(uint_t* __restrict__ p, int n) {
    int i = blockIdx.x * blockDim.x + threadIdx.x;
    if (i < n) p[i] = 0u;
}

// ---------- custom grid barrier (agent-scope, LLC-resident, no L2 wb/inv) ----------
__device__ __forceinline__ void gridbar(uint_t* cnt, uint_t* flag, unsigned tgt) {
    __syncthreads();   // all WG stores complete (vmcnt(0) before s_barrier)
    if (threadIdx.x == 0) {
        unsigned old = __hip_atomic_fetch_add(cnt, 1u, __ATOMIC_ACQ_REL, __HIP_MEMORY_SCOPE_AGENT);
        if (old == tgt * NWG - 1u) {
            __hip_atomic_store(flag, tgt, __ATOMIC_RELEASE, __HIP_MEMORY_SCOPE_AGENT);
        } else {
            while (__hip_atomic_load(flag, __ATOMIC_RELAXED, __HIP_MEMORY_SCOPE_AGENT) < tgt) {}
            (void)__hip_atomic_load(flag, __ATOMIC_ACQUIRE, __HIP_MEMORY_SCOPE_AGENT);
        }
    }
    __syncthreads();
}

// ---------- load 8 packed h-values (hi|lo) as two bf16x8 fragments ----------
__device__ __forceinline__ void loadH8(const uint_t* q, bf16x8& hi, bf16x8& lo) {
    unsigned long long a0 = __hip_atomic_load((const unsigned long long*)(q + 0), __ATOMIC_RELAXED, __HIP_MEMORY_SCOPE_AGENT);
    unsigned long long a1 = __hip_atomic_load((const unsigned long long*)(q + 2), __ATOMIC_RELAXED, __HIP_MEMORY_SCOPE_AGENT);
    unsigned long long a2 = __hip_atomic_load((const unsigned long long*)(q + 4), __ATOMIC_RELAXED, __HIP_MEMORY_SCOPE_AGENT);
    unsigned long long a3 = __hip_atomic_load((const unsigned long long*)(q + 6), __ATOMIC_RELAXED, __HIP_MEMORY_SCOPE_AGENT);
    unsigned u0 = (unsigned)a0, u1 = (unsigned)(a0 >> 32);
    unsigned u2 = (unsigned)a1, u3 = (unsigned)(a1 >> 32);
    unsigned u4 = (unsigned)a2, u5 = (unsigned)(a2 >> 32);
    unsigned u6 = (unsigned)a3, u7 = (unsigned)(a3 >> 32);
    union { bf16x8 v; unsigned u[4]; } H, L;
    H.u[0] = __builtin_amdgcn_perm(u1, u0, 0x05040100u);
    L.u[0] = __builtin_amdgcn_perm(u1, u0, 0x07060302u);
    H.u[1] = __builtin_amdgcn_perm(u3, u2, 0x05040100u);
    L.u[1] = __builtin_amdgcn_perm(u3, u2, 0x07060302u);
    H.u[2] = __builtin_amdgcn_perm(u5, u4, 0x05040100u);
    L.u[2] = __builtin_amdgcn_perm(u5, u4, 0x07060302u);
    H.u[3] = __builtin_amdgcn_perm(u7, u6, 0x05040100u);
    L.u[3] = __builtin_amdgcn_perm(u7, u6, 0x07060302u);
    hi = H.v; lo = L.v;
}

// ---------- main persistent cooperative kernel ----------
// 256 WGs x 128 threads (2 waves). WG w: layer = w>>7; u=(w>>2)&31; bt=w&3.
__global__ __launch_bounds__(128, 1) void lstm_main(
    const ushort_t* __restrict__ XeHi,
    uint_t* __restrict__ Hc0, uint_t* __restrict__ Hc1,
    uint_t* __restrict__ bar,
    const ushort_t* __restrict__ B0hi, const ushort_t* __restrict__ B0lo,
    const ushort_t* __restrict__ B1hi, const ushort_t* __restrict__ B1lo,
    const float* __restrict__ bias0, const float* __restrict__ bias1,
    const float* __restrict__ Wclf, const float* __restrict__ bclf,
    float* __restrict__ out)
{
    __shared__ float red[4][4][64];
    __shared__ ushort_t wlds[NL * 8 * 512];   // 144KB weight cache

    uint_t* cnt  = bar;
    uint_t* flag = bar + 32;   // separate 128B line

    const int lane = threadIdx.x & 63;
    const int wv   = threadIdx.x >> 6;          // 0 or 1
    const int wg   = blockIdx.x;
    const int layer = wg >> 7;
    const int rr   = wg & 127;
    const int u    = rr >> 2;
    const int bt   = rr & 3;
    const int KS   = layer ? 32 : 24;
    const ushort_t* Bhi = layer ? B1hi : B0hi;
    const ushort_t* Blo = layer ? B1lo : B0lo;
    const float* bias   = layer ? bias1 : bias0;

    // per-wave k-slice schedule: nc cached + nr residual
    const int nc   = NL / 2;                            // 9
    const int cBeg = wv ? NL / 2 : 0;
    const int rBeg = NL + (wv ? (KS - NL) / 2 : 0);
    const int nr   = (KS - NL) / 2;                     // 3 (L0) or 7 (L1)
    const int n    = nc + nr;

    // hoisted per-lane constants
    const int rowA = bt * 16 + (lane & 15);     // batch row for A-frags
    const int koffA = (lane >> 4) * 8;
    const size_t gs    = (size_t)KS * 512;      // gate stride in packed B
    const size_t bBase = (size_t)(u * 4) * gs + (size_t)lane * 8;
    float bg0 = bias[0 * HDIM + u * 16 + (lane & 15)];
    float bg1 = bias[1 * HDIM + u * 16 + (lane & 15)];
    float bg2 = bias[2 * HDIM + u * 16 + (lane & 15)];
    float bg3 = bias[3 * HDIM + u * 16 + (lane & 15)];

    // ---- stage weight k-slices [0, NL) into LDS (once) ----
    for (int fid = wv; fid < NL * 8; fid += 2) {
        int ks  = fid >> 3;
        int buf = (fid >> 2) & 1;
        int g   = fid & 3;
        const ushort_t* src = (buf ? Blo : Bhi) + bBase + (size_t)g * gs + (size_t)ks * 512;
        *(bf16x8*)(wlds + (size_t)fid * 512 + lane * 8) = *(const bf16x8*)src;
    }
    __syncthreads();

    f32x4 cst = {0.f, 0.f, 0.f, 0.f};           // persistent c-state (owner wave)

    for (int p = 0; p <= T_STEPS; ++p) {
        const bool active = layer ? (p >= 1) : (p < T_STEPS);
        f32x4 acc0 = {0,0,0,0}, acc1 = {0,0,0,0}, acc2 = {0,0,0,0}, acc3 = {0,0,0,0};

        if (active) {
            auto ksOf = [&](int i) { return (i < nc) ? (cBeg + i) : (rBeg + (i - nc)); };
            // ---- A fragments: XeHi plain, h-state via agent-scope LLC loads ----
            auto loadA = [&](int ks, bf16x8& ah, bf16x8& al, int& haslo) {
                if (layer == 0 && ks < 8) {
                    const ushort_t* hi = XeHi + (size_t)p * (BATCH * EDIM);
                    ah = *(const bf16x8*)(hi + (size_t)rowA * EDIM + ks * 32 + koffA);
                    haslo = 0;
                    return;
                }
                const uint_t* Hc; int kl;
                if (layer == 0)      { Hc = Hc0 + (size_t)((p - 1) & 1) * HB; kl = ks - 8; }
                else if (ks < 16)    { Hc = Hc0 + (size_t)((p - 1) & 1) * HB; kl = ks; }
                else                 { Hc = Hc1 + (size_t)(p & 1) * HB;       kl = ks - 16; }
                loadH8(Hc + (size_t)rowA * HDIM + kl * 32 + koffA, ah, al);
                haslo = 1;
            };
            // ---- B fragments: LDS if cached, else global (plain, L2-resident) ----
            auto loadB = [&](int i, bf16x8* bh, bf16x8* bl) {
                int ks = ksOf(i);
                if (i < nc) {
                    const ushort_t* p8 = wlds + (size_t)(8 * ks) * 512 + lane * 8;
                    #pragma unroll
                    for (int g = 0; g < 4; ++g) {
                        bh[g] = *(const bf16x8*)(p8 + (size_t)g * 512);
                        bl[g] = *(const bf16x8*)(p8 + (size_t)(4 + g) * 512);
                    }
                } else {
                    const size_t o = bBase + (size_t)ks * 512;
                    #pragma unroll
                    for (int g = 0; g < 4; ++g) {
                        bh[g] = *(const bf16x8*)(Bhi + o + g * gs);
                        bl[g] = *(const bf16x8*)(Blo + o + g * gs);
                    }
                }
            };

            bf16x8 cah, cal, cbh[4], cbl[4]; int chl;
            loadA(ksOf(0), cah, cal, chl);
            loadB(0, cbh, cbl);
            #pragma unroll 2
            for (int i = 0; i < n; ++i) {
                bf16x8 nah = cah, nal = cal, nbh[4], nbl[4]; int nhl = chl;
                #pragma unroll
                for (int g = 0; g < 4; ++g) { nbh[g] = cbh[g]; nbl[g] = cbl[g]; }
                if (i + 1 < n) {
                    loadA(ksOf(i + 1), nah, nal, nhl);
                    loadB(i + 1, nbh, nbl);
                }
                acc0 = __builtin_amdgcn_mfma_f32_16x16x32_bf16(cah, cbh[0], acc0, 0, 0, 0);
                acc1 = __builtin_amdgcn_mfma_f32_16x16x32_bf16(cah, cbh[1], acc1, 0, 0, 0);
                acc2 = __builtin_amdgcn_mfma_f32_16x16x32_bf16(cah, cbh[2], acc2, 0, 0, 0);
                acc3 = __builtin_amdgcn_mfma_f32_16x16x32_bf16(cah, cbh[3], acc3, 0, 0, 0);
                acc0 = __builtin_amdgcn_mfma_f32_16x16x32_bf16(cah, cbl[0], acc0, 0, 0, 0);
                acc1 = __builtin_amdgcn_mfma_f32_16x16x32_bf16(cah, cbl[1], acc1, 0, 0, 0);
                acc2 = __builtin_amdgcn_mfma_f32_16x16x32_bf16(cah, cbl[2], acc2, 0, 0, 0);
                acc3 = __builtin_amdgcn_mfma_f32_16x16x32_bf16(cah, cbl[3], acc3, 0, 0, 0);
                if (chl) {
                    acc0 = __builtin_amdgcn_mfma_f32_16x16x32_bf16(cal, cbh[0], acc0, 0, 0, 0);
                    acc1 = __builtin_amdgcn_mfma_f32_16x16x32_bf16(cal, cbh[1], acc1, 0, 0, 0);
                    acc2 = __builtin_amdgcn_mfma_f32_16x16x32_bf16(cal, cbh[2], acc2, 0, 0, 0);
                    acc3 = __builtin_amdgcn_mfma_f32_16x16x32_bf16(cal, cbh[3], acc3, 0, 0, 0);
                }
                cah = nah; cal = nal; chl = nhl;
                #pragma unroll
                for (int g = 0; g < 4; ++g) { cbh[g] = nbh[g]; cbl[g] = nbl[g]; }
            }

            if (wv == 1) {
                #pragma unroll
                for (int r = 0; r < 4; ++r) {
                    red[0][r][lane] = acc0[r];
                    red[1][r][lane] = acc1[r];
                    red[2][r][lane] = acc2[r];
                    red[3][r][lane] = acc3[r];
                }
            }
        }
        __syncthreads();
        if (active && wv == 0) {
            uint_t* Wc = layer ? (Hc1 + (size_t)((p - 1) & 1) * HB) : (Hc0 + (size_t)(p & 1) * HB);
            #pragma unroll
            for (int r = 0; r < 4; ++r) {
                float gi = acc0[r] + red[0][r][lane] + bg0;
                float gf = acc1[r] + red[1][r][lane] + bg1;
                float gg = acc2[r] + red[2][r][lane] + bg2;
                float go = acc3[r] + red[3][r][lane] + bg3;
                float ig = sigm(gi), fg = sigm(gf), gc = tanh_f(gg), og = sigm(go);
                float cn = fg * cst[r] + ig * gc;
                cst[r] = cn;
                float h = og * tanh_f(cn);
                int b = bt * 16 + (lane >> 4) * 4 + r;
                int cidx = u * 16 + (lane & 15);
                unsigned short hh = f2bf(h);
                float hf = bf2f(hh);
                unsigned short hl = f2bf(h - hf);
                uint_t val = (uint_t)hh | ((uint_t)hl << 16);
                __hip_atomic_store(Wc + (size_t)b * HDIM + cidx, val, __ATOMIC_RELAXED, __HIP_MEMORY_SCOPE_AGENT);
            }
        }
        gridbar(cnt, flag, (unsigned)(p + 1));
    }

    // ---------- classifier: out = h1_final @ Wclf^T + bclf ----------
    if (wg == 0 && wv == 0) {
        int b = lane;
        float a0 = bclf[0], a1 = bclf[1];
        const uint_t* hf = Hc1 + HB;   // final h1 in slot 1
        #pragma unroll 8
        for (int k = 0; k < HDIM; ++k) {
            uint_t v = __hip_atomic_load(hf + (size_t)b * HDIM + k, __ATOMIC_RELAXED, __HIP_MEMORY_SCOPE_AGENT);
            float h = bf2f((unsigned short)v) + bf2f((unsigned short)(v >> 16));
            a0 = fmaf(h, Wclf[k], a0);
            a1 = fmaf(h, Wclf[HDIM + k], a1);
        }
        out[b * 2 + 0] = a0;
        out[b * 2 + 1] = a1;
    }
}

extern "C" void kernel_launch(void* const* d_in, const int* in_sizes, int n_in,
                              void* d_out, int out_size, void* d_ws, size_t ws_size,
                              hipStream_t stream) {
    const int*   x     = (const int*)d_in[0];
    const float* emb   = (const float*)d_in[1];
    const float* Wih0  = (const float*)d_in[2];
    const float* Whh0  = (const float*)d_in[3];
    const float* bias0 = (const float*)d_in[4];
    const float* Wih1  = (const float*)d_in[5];
    const float* Whh1  = (const float*)d_in[6];
    const float* bias1 = (const float*)d_in[7];
    const float* Wclf  = (const float*)d_in[8];
    const float* bclf  = (const float*)d_in[9];
    float* out = (float*)d_out;

    char* base = (char*)d_ws;
    ushort_t* XeHi = (ushort_t*)(base + BYTE_XEHI);
    uint_t*   Hc0  = (uint_t*)(base + BYTE_HC0);
    uint_t*   Hc1  = (uint_t*)(base + BYTE_HC1);
    uint_t*   bar  = (uint_t*)(base + BYTE_BAR);
    ushort_t* B0hi = (ushort_t*)(base + BYTE_B0HI);
    ushort_t* B0lo = (ushort_t*)(base + BYTE_B0LO);
    ushort_t* B1hi = (ushort_t*)(base + BYTE_B1HI);
    ushort_t* B1lo = (ushort_t*)(base + BYTE_B1LO);

    // 1) gather+convert embeddings
    xepack_kernel<<<4096, 256, 0, stream>>>(x, emb, XeHi);
    // 2) pack weights (hi/lo) to fragment order
    wpack_kernel<<<1793, 256, 0, stream>>>(Wih0, Whh0, Wih1, Whh1, B0hi, B0lo, B1hi, B1lo);
    // 3) zero h-state (4*HB uints) + barrier vars (64 uints), contiguous at Hc0
    zero_kernel<<<513, 256, 0, stream>>>(Hc0, 4 * HB + 64);
    // 4) persistent cooperative LSTM
    void* args[] = {
        (void*)&XeHi, (void*)&Hc0, (void*)&Hc1, (void*)&bar,
        (void*)&B0hi, (void*)&B0lo, (void*)&B1hi, (void*)&B1lo,
        (void*)&bias0, (void*)&bias1,
        (void*)&Wclf, (void*)&bclf,
        (void*)&out
    };
    hipLaunchCooperativeKernel((void*)lstm_main, dim3(NWG), dim3(128), args, 0, stream);
}